// Round 12
// baseline (95.783 us; speedup 1.0000x reference)
//
#include <hip/hip_runtime.h>

// Mutual information, N=8 images 384x384, 50 soft bins.
// K1 hgram: 28 even sigmoid edges per element (t_j = sigmoid(10v-0.2j), x256),
//   G = te_x . te_y^T via 32x32x16 MFMA, K split across the 4 waves
//   (wave w: k in [64w,64w+64) per 256-chunk), cross-wave LDS reduce, atomic
//   28x28 epilogue into hg[8][32][32] (zeroed by 32KB memset dispatch).
// K2 finalize (1 block): hgram = W G W^T, W = D*M (cubic-interp odd edges,
//   4-banded {1,7,-9,1}/16 even, {-1,9,-7,-1}/16 odd); marginals telescope
//   (sum_b W[b] = e_1 - e_26); MI log-sum.
//
// R12 vs R11 (hgram is LDS-inst-bound: 112 b32 writes + 64 b128 reads/iter):
//  (a) 32x32x16 MFMA + wave-K-split halves frag reads (64->32 b128);
//  (b) 4-elem staging quads, 2x pkrtz -> ds_write_b64 halves writes (112->56);
//      staging alternates wave-pairs per iter (0,1 even / 2,3 odd) to keep
//      trans-pipe work balanced across SIMDs.

#define D_TOTAL   147456
#define NBATCH    8
#define BINS      50
#define NEDGE     28                       // even edges j=-2..52
#define KSLICES   96                       // 768 blocks = 3/CU, single generation
#define KC        256                      // d-columns per block iteration
#define SLICE_LEN (D_TOTAL / KSLICES)      // 1536
#define ITERS     (SLICE_LEN / KC)         // 6 (even: each wave-pair stages 3)
#define LDS_STR   280                      // 140 dwords = 12 mod 32: conflict-free b128 frags

typedef _Float16 half8  __attribute__((ext_vector_type(8)));
typedef __fp16   fp16x2 __attribute__((ext_vector_type(2)));   // cvt_pkrtz return type
typedef float    f32x4  __attribute__((ext_vector_type(4)));
typedef float    f32x16 __attribute__((ext_vector_type(16)));

struct Tab { float c[NEDGE]; };
constexpr Tab make_tab() {
    Tab t{};
    double c = 0.6703200460356393;          // e^{-0.4} (edge j=-2)
    const double lam = 1.4918246976412703;  // e^{0.4} between even edges
    for (int i = 0; i < NEDGE; ++i) { t.c[i] = (float)c; c *= lam; }
    return t;
}
constexpr Tab TAB = make_tab();

__global__ __launch_bounds__(256, 3) void hgram_kernel(const float* __restrict__ im1,
                                                       const float* __restrict__ im2,
                                                       float* __restrict__ hg) {
    __shared__ __align__(16) _Float16 Xs[32][LDS_STR];
    __shared__ __align__(16) _Float16 Ys[32][LDS_STR];

    const int tid   = threadIdx.x;
    const int slice = blockIdx.x;
    const int n     = blockIdx.y;
    const int base  = n * D_TOTAL + slice * SLICE_LEN;

    {   // zero pad rows 28..31 once (staging only rewrites rows 0..27)
        unsigned* px = (unsigned*)&Xs[28][0];
        unsigned* py = (unsigned*)&Ys[28][0];
        for (int i = tid; i < 4 * LDS_STR / 2; i += 256) { px[i] = 0u; py[i] = 0u; }
    }

    const int lane = tid & 63;
    const int sw   = tid >> 6;                // wave id 0..3
    const int pair = sw >> 1;                 // stages even iters (0) / odd iters (1)
    const int isY  = sw & 1;                  // within pair: X / Y plane
    const float4* src4 = (const float4*)((isY ? im2 : im1) + base);
    _Float16* dst = (isY ? &Ys[0][0] : &Xs[0][0]) + 4 * lane;   // elem quad 4*lane..+3

    // stage 4 elements: 28 even-edge sigmoids each (x256), packed b64 writes
    auto stage = [&](float4 v) {
        const float E0 = __builtin_amdgcn_exp2f(v.x * -14.426950408889634f);
        const float E1 = __builtin_amdgcn_exp2f(v.y * -14.426950408889634f);
        const float E2 = __builtin_amdgcn_exp2f(v.z * -14.426950408889634f);
        const float E3 = __builtin_amdgcn_exp2f(v.w * -14.426950408889634f);
        #pragma unroll
        for (int i = 0; i < NEDGE; ++i) {
            const float c = TAB.c[i];         // compile-time literal
            float t0 = __builtin_amdgcn_rcpf(__builtin_fmaf(c * E0, 0.00390625f, 0.00390625f));
            float t1 = __builtin_amdgcn_rcpf(__builtin_fmaf(c * E1, 0.00390625f, 0.00390625f));
            float t2 = __builtin_amdgcn_rcpf(__builtin_fmaf(c * E2, 0.00390625f, 0.00390625f));
            float t3 = __builtin_amdgcn_rcpf(__builtin_fmaf(c * E3, 0.00390625f, 0.00390625f));
            uint2 U;
            U.x = __builtin_bit_cast(unsigned, __builtin_amdgcn_cvt_pkrtz(t0, t1));
            U.y = __builtin_bit_cast(unsigned, __builtin_amdgcn_cvt_pkrtz(t2, t3));
            *(uint2*)(dst + i * LDS_STR) = U;  // one ds_write_b64
        }
    };

    f32x16 acc = {0.f};
    const int arow = lane & 31;               // G row (A) / col (B) index
    const int kgrp = (lane >> 5) << 3;        // k sub-group 0/8

    float4 v = src4[pair * (KC / 4) * 1 + lane + (pair ? (KC / 4) - (KC / 4) : 0)];
    // ^ pair0 loads iter0 (src4[lane]); pair1 loads iter1 (src4[64+lane]):
    v = pair ? src4[(KC / 4) + lane] : src4[lane];

    for (int it = 0; it < ITERS; ++it) {
        if ((it & 1) == pair) {
            float4 nv = {0.f, 0.f, 0.f, 0.f};
            if (it + 2 < ITERS) nv = src4[(it + 2) * (KC / 4) + lane];  // prefetch
            stage(v);
            v = nv;
        }
        __syncthreads();   // staged plane ready; prior MFMA readers done
        #pragma unroll
        for (int ks = 0; ks < 4; ++ks) {
            const int k0 = sw * 64 + ks * 16 + kgrp;
            half8 a = *(const half8*)&Xs[arow][k0];
            half8 b = *(const half8*)&Ys[arow][k0];
            acc = __builtin_amdgcn_mfma_f32_32x32x16_f16(a, b, acc, 0, 0, 0);
        }
        __syncthreads();
    }

    // cross-wave reduce of the 4 k-partial 32x32 tiles via LDS scratch (16KB in Xs)
    float* scratch = (float*)&Xs[0][0];
    #pragma unroll
    for (int r = 0; r < 16; ++r) {
        const int row = (r & 3) + 8 * (r >> 2) + 4 * (lane >> 5);   // C/D mapping
        scratch[sw * 1024 + row * 32 + (lane & 31)] = acc[r];
    }
    __syncthreads();
    {
        f32x4 s = *(const f32x4*)&scratch[4 * tid];
        s += *(const f32x4*)&scratch[1024 + 4 * tid];
        s += *(const f32x4*)&scratch[2048 + 4 * tid];
        s += *(const f32x4*)&scratch[3072 + 4 * tid];
        float* hgn = hg + n * 1024;
        const int row = tid >> 3, col0 = (tid & 7) << 2;
        if (row < NEDGE) {
            #pragma unroll
            for (int j = 0; j < 4; ++j)
                if (col0 + j < NEDGE) atomicAdd(&hgn[row * 32 + col0 + j], s[j]);
        }
    }
}

__global__ __launch_bounds__(1024) void finalize_kernel(const float* __restrict__ hg,
                                                        float* __restrict__ out) {
    __shared__ float Gs[NBATCH][NEDGE][29];   // stride 29 vs bank conflicts
    __shared__ float mx[NBATCH][BINS], my[NBATCH][BINS];
    __shared__ float red[16];
    __shared__ float sT;
    const int tid = threadIdx.x;

    for (int idx = tid; idx < NBATCH * NEDGE * NEDGE; idx += 1024) {
        int n = idx / (NEDGE * NEDGE);
        int rem = idx - n * (NEDGE * NEDGE);
        int r = rem / NEDGE, c = rem - r * NEDGE;
        Gs[n][r][c] = hg[n * 1024 + r * 32 + c];
    }
    __syncthreads();

    // marginals: 800 tasks, 4-MAC band-dot (W row applied to G*(e1-e26))
    if (tid < 2 * NBATCH * BINS) {
        const int which = (tid >= NBATCH * BINS) ? 1 : 0;
        const int t2 = which ? tid - NBATCH * BINS : tid;
        const int n = t2 / BINS, b = t2 - n * BINS;
        const int q = b >> 1;
        float w0, w1, w2, w3;
        if (b & 1) { w0 = -1.f; w1 = 9.f; w2 = -7.f; w3 = -1.f; }
        else       { w0 =  1.f; w1 = 7.f; w2 = -9.f; w3 =  1.f; }
        float m;
        if (which == 0) {
            m = w0 * (Gs[n][q][1]   - Gs[n][q][26])
              + w1 * (Gs[n][q+1][1] - Gs[n][q+1][26])
              + w2 * (Gs[n][q+2][1] - Gs[n][q+2][26])
              + w3 * (Gs[n][q+3][1] - Gs[n][q+3][26]);
            mx[n][b] = m * 0.0625f;
        } else {
            m = w0 * (Gs[n][1][q]   - Gs[n][26][q])
              + w1 * (Gs[n][1][q+1] - Gs[n][26][q+1])
              + w2 * (Gs[n][1][q+2] - Gs[n][26][q+2])
              + w3 * (Gs[n][1][q+3] - Gs[n][26][q+3]);
            my[n][b] = m * 0.0625f;
        }
    }
    if (tid == 0) {
        float t = 0.f;
        for (int n = 0; n < NBATCH; ++n)
            t += Gs[n][1][1] - Gs[n][1][26] - Gs[n][26][1] + Gs[n][26][26];
        sT = t;
    }
    __syncthreads();

    // MI pass: 2x2 entry blocks share one 4x4 G block (task = n, b-pair, c-pair)
    const float invT = 1.0f / sT;
    const float invT2 = invT * invT;
    float mi = 0.f;
    for (int task = tid; task < NBATCH * 25 * 25; task += 1024) {
        const int n = task / 625;
        const int rem = task - n * 625;
        const int bp = rem / 25, cp = rem - bp * 25;
        float g[4][4];
        #pragma unroll
        for (int r = 0; r < 4; ++r)
            #pragma unroll
            for (int s = 0; s < 4; ++s) g[r][s] = Gs[n][bp + r][cp + s];
        float rde[4], rdo[4];
        #pragma unroll
        for (int r = 0; r < 4; ++r) {
            rde[r] =  g[r][0] + 7.f * g[r][1] - 9.f * g[r][2] + g[r][3];
            rdo[r] = -g[r][0] + 9.f * g[r][1] - 7.f * g[r][2] - g[r][3];
        }
        const float hee = ( rde[0] + 7.f*rde[1] - 9.f*rde[2] + rde[3]) * (1.f/256.f);
        const float heo = ( rdo[0] + 7.f*rdo[1] - 9.f*rdo[2] + rdo[3]) * (1.f/256.f);
        const float hoe = (-rde[0] + 9.f*rde[1] - 7.f*rde[2] - rde[3]) * (1.f/256.f);
        const float hoo = (-rdo[0] + 9.f*rdo[1] - 7.f*rdo[2] - rdo[3]) * (1.f/256.f);
        const int b0 = 2 * bp, c0 = 2 * cp;
        {
            float p = hee * invT, jo = mx[n][b0] * my[n][c0] * invT2;
            mi += p * (__logf(p + 1e-8f) - __logf(jo + 1e-8f));
        }
        {
            float p = heo * invT, jo = mx[n][b0] * my[n][c0 + 1] * invT2;
            mi += p * (__logf(p + 1e-8f) - __logf(jo + 1e-8f));
        }
        {
            float p = hoe * invT, jo = mx[n][b0 + 1] * my[n][c0] * invT2;
            mi += p * (__logf(p + 1e-8f) - __logf(jo + 1e-8f));
        }
        {
            float p = hoo * invT, jo = mx[n][b0 + 1] * my[n][c0 + 1] * invT2;
            mi += p * (__logf(p + 1e-8f) - __logf(jo + 1e-8f));
        }
    }
    #pragma unroll
    for (int o = 32; o > 0; o >>= 1) mi += __shfl_down(mi, o, 64);
    if ((tid & 63) == 0) red[tid >> 6] = mi;
    __syncthreads();
    if (tid == 0) {
        float t = 0.f;
        for (int i = 0; i < 16; ++i) t += red[i];
        out[0] = t;
    }
}

extern "C" void kernel_launch(void* const* d_in, const int* in_sizes, int n_in,
                              void* d_out, int out_size, void* d_ws, size_t ws_size,
                              hipStream_t stream) {
    const float* im1 = (const float*)d_in[0];
    const float* im2 = (const float*)d_in[1];
    float* out = (float*)d_out;
    float* hg  = (float*)d_ws;   // [8][32][32] f32 = 32 KB

    (void)hipMemsetAsync(d_ws, 0, NBATCH * 1024 * sizeof(float), stream);
    hgram_kernel<<<dim3(KSLICES, NBATCH), dim3(256), 0, stream>>>(im1, im2, hg);
    finalize_kernel<<<dim3(1), dim3(1024), 0, stream>>>(hg, out);
}

// Round 13
// 83.270 us; speedup vs baseline: 1.1503x; 1.1503x over previous
//
#include <hip/hip_runtime.h>

// Mutual information, N=8 images 384x384, 50 soft bins.
// K1 hgram: 28 even sigmoid edges per element (t_j = sigmoid(10v-0.2j), x256),
//   G = te_x . te_y^T via 16x16x32 MFMA (32x32-padded), atomic 28x28 epilogue
//   into hg[8][32][32] (zeroed by a 32KB memset dispatch).
// K2 finalize (1 block): hgram = W G W^T, W = D*M (cubic-interp odd edges,
//   4-banded {1,7,-9,1}/16 even, {-1,9,-7,-1}/16 odd); marginals telescope
//   (sum_b W[b] = e_1 - e_26); MI log-sum.
//
// R13 = R11 verbatim (best: 82.75us). R12's wave-specialized staging + 32x32
// K-split regressed to 95.8us: halving ds-inst totals doubled the per-barrier
// critical path (2 staging waves x 112 rcp vs 4 waves x 56) — in a
// barrier-synced loop, balance per-wave latency, not instruction counts.
// Budget: ~68us fixed harness floor (256MB ws re-poison fill @83% HBM + input
// restores + gaps) + hgram ~9us + memset/finalize dispatches ~6us.

#define D_TOTAL   147456
#define NBATCH    8
#define BINS      50
#define NEDGE     28                       // even edges j=-2..52
#define KSLICES   96                       // 768 blocks = 3/CU, single generation
#define KC        256                      // d-columns per block iteration
#define SLICE_LEN (D_TOTAL / KSLICES)      // 1536
#define ITERS     (SLICE_LEN / KC)         // 6
#define LDS_STR   280                      // 140 dwords = 12 mod 32: conflict-free b128 frags

typedef _Float16 half8  __attribute__((ext_vector_type(8)));
typedef __fp16   fp16x2 __attribute__((ext_vector_type(2)));   // cvt_pkrtz return type
typedef float    f32x4  __attribute__((ext_vector_type(4)));

struct Tab { float c[NEDGE]; };
constexpr Tab make_tab() {
    Tab t{};
    double c = 0.6703200460356393;          // e^{-0.4} (edge j=-2)
    const double lam = 1.4918246976412703;  // e^{0.4} between even edges
    for (int i = 0; i < NEDGE; ++i) { t.c[i] = (float)c; c *= lam; }
    return t;
}
constexpr Tab TAB = make_tab();

__global__ __launch_bounds__(256, 3) void hgram_kernel(const float* __restrict__ im1,
                                                       const float* __restrict__ im2,
                                                       float* __restrict__ hg) {
    __shared__ __align__(16) _Float16 Xs[32][LDS_STR];
    __shared__ __align__(16) _Float16 Ys[32][LDS_STR];

    const int tid   = threadIdx.x;
    const int slice = blockIdx.x;
    const int n     = blockIdx.y;
    const int base  = n * D_TOTAL + slice * SLICE_LEN;

    {   // zero pad rows 28..31 once (staging only rewrites rows 0..27)
        unsigned* px = (unsigned*)&Xs[28][0];
        unsigned* py = (unsigned*)&Ys[28][0];
        for (int i = tid; i < 4 * LDS_STR / 2; i += 256) { px[i] = 0u; py[i] = 0u; }
    }

    // staging: threads 0..127 stage X element-pair (2h, 2h+1); 128..255 stage Y
    const int h    = tid & 127;
    const int isY  = tid >> 7;
    const float2* src2 = (const float2*)((isY ? im2 : im1) + base);
    _Float16* plane = isY ? &Ys[0][0] : &Xs[0][0];
    _Float16* dst   = plane + 2 * h;            // pair base within row

    const int lane = tid & 63;
    const int w    = tid >> 6;
    const int r0   = (w & 1) << 4;              // G row strip (X edge)
    const int c0   = (w >> 1) << 4;             // G col strip (Y edge)
    const int frow = lane & 15;
    const int kg   = (lane >> 4) << 3;

    f32x4 acc = {0.f, 0.f, 0.f, 0.f};

    float2 v = src2[h];
    for (int it = 0; it < ITERS; ++it) {
        float2 nv = {0.f, 0.f};
        if (it + 1 < ITERS) nv = src2[(it + 1) * (KC / 2) + h];   // prefetch
        // ---- stage 2 elements: 28 even-edge sigmoids each (x256, f16, packed) ----
        {
            const float Ea = __builtin_amdgcn_exp2f(v.x * -14.426950408889634f); // e^{-10va}
            const float Eb = __builtin_amdgcn_exp2f(v.y * -14.426950408889634f); // e^{-10vb}
            #pragma unroll
            for (int i = 0; i < NEDGE; ++i) {
                const float c = TAB.c[i];       // compile-time literal
                float ta = __builtin_amdgcn_rcpf(__builtin_fmaf(c * Ea, 0.00390625f, 0.00390625f));
                float tb = __builtin_amdgcn_rcpf(__builtin_fmaf(c * Eb, 0.00390625f, 0.00390625f));
                fp16x2 p = __builtin_amdgcn_cvt_pkrtz(ta, tb);    // 256/(1+u) pair
                *(fp16x2*)(dst + i * LDS_STR) = p;                // one ds_write_b32
            }
        }
        __syncthreads();
        #pragma unroll
        for (int ks = 0; ks < 8; ++ks) {
            const int k0 = ks * 32 + kg;
            half8 a = *(const half8*)&Xs[r0 + frow][k0];
            half8 b = *(const half8*)&Ys[c0 + frow][k0];
            acc = __builtin_amdgcn_mfma_f32_16x16x32_f16(a, b, acc, 0, 0, 0);
        }
        __syncthreads();
        v = nv;
    }

    // epilogue: atomic-add the 28x28 region of G
    float* hgn = hg + n * 1024;
    const int gj = c0 + (lane & 15);
    const int ri = r0 + ((lane >> 4) << 2);
    if (gj < NEDGE) {
        #pragma unroll
        for (int r = 0; r < 4; ++r) {
            const int gi = ri + r;
            if (gi < NEDGE) atomicAdd(&hgn[gi * 32 + gj], acc[r]);
        }
    }
}

__global__ __launch_bounds__(1024) void finalize_kernel(const float* __restrict__ hg,
                                                        float* __restrict__ out) {
    __shared__ float Gs[NBATCH][NEDGE][29];   // stride 29 vs bank conflicts
    __shared__ float mx[NBATCH][BINS], my[NBATCH][BINS];
    __shared__ float red[16];
    __shared__ float sT;
    const int tid = threadIdx.x;

    for (int idx = tid; idx < NBATCH * NEDGE * NEDGE; idx += 1024) {
        int n = idx / (NEDGE * NEDGE);
        int rem = idx - n * (NEDGE * NEDGE);
        int r = rem / NEDGE, c = rem - r * NEDGE;
        Gs[n][r][c] = hg[n * 1024 + r * 32 + c];
    }
    __syncthreads();

    // marginals: 800 tasks, 4-MAC band-dot (W row applied to G*(e1-e26))
    if (tid < 2 * NBATCH * BINS) {
        const int which = (tid >= NBATCH * BINS) ? 1 : 0;
        const int t2 = which ? tid - NBATCH * BINS : tid;
        const int n = t2 / BINS, b = t2 - n * BINS;
        const int q = b >> 1;
        float w0, w1, w2, w3;
        if (b & 1) { w0 = -1.f; w1 = 9.f; w2 = -7.f; w3 = -1.f; }
        else       { w0 =  1.f; w1 = 7.f; w2 = -9.f; w3 =  1.f; }
        float m;
        if (which == 0) {
            m = w0 * (Gs[n][q][1]   - Gs[n][q][26])
              + w1 * (Gs[n][q+1][1] - Gs[n][q+1][26])
              + w2 * (Gs[n][q+2][1] - Gs[n][q+2][26])
              + w3 * (Gs[n][q+3][1] - Gs[n][q+3][26]);
            mx[n][b] = m * 0.0625f;
        } else {
            m = w0 * (Gs[n][1][q]   - Gs[n][26][q])
              + w1 * (Gs[n][1][q+1] - Gs[n][26][q+1])
              + w2 * (Gs[n][1][q+2] - Gs[n][26][q+2])
              + w3 * (Gs[n][1][q+3] - Gs[n][26][q+3]);
            my[n][b] = m * 0.0625f;
        }
    }
    if (tid == 0) {
        float t = 0.f;
        for (int n = 0; n < NBATCH; ++n)
            t += Gs[n][1][1] - Gs[n][1][26] - Gs[n][26][1] + Gs[n][26][26];
        sT = t;
    }
    __syncthreads();

    // MI pass: 2x2 entry blocks share one 4x4 G block (task = n, b-pair, c-pair)
    const float invT = 1.0f / sT;
    const float invT2 = invT * invT;
    float mi = 0.f;
    for (int task = tid; task < NBATCH * 25 * 25; task += 1024) {
        const int n = task / 625;
        const int rem = task - n * 625;
        const int bp = rem / 25, cp = rem - bp * 25;
        float g[4][4];
        #pragma unroll
        for (int r = 0; r < 4; ++r)
            #pragma unroll
            for (int s = 0; s < 4; ++s) g[r][s] = Gs[n][bp + r][cp + s];
        float rde[4], rdo[4];
        #pragma unroll
        for (int r = 0; r < 4; ++r) {
            rde[r] =  g[r][0] + 7.f * g[r][1] - 9.f * g[r][2] + g[r][3];
            rdo[r] = -g[r][0] + 9.f * g[r][1] - 7.f * g[r][2] - g[r][3];
        }
        const float hee = ( rde[0] + 7.f*rde[1] - 9.f*rde[2] + rde[3]) * (1.f/256.f);
        const float heo = ( rdo[0] + 7.f*rdo[1] - 9.f*rdo[2] + rdo[3]) * (1.f/256.f);
        const float hoe = (-rde[0] + 9.f*rde[1] - 7.f*rde[2] - rde[3]) * (1.f/256.f);
        const float hoo = (-rdo[0] + 9.f*rdo[1] - 7.f*rdo[2] - rdo[3]) * (1.f/256.f);
        const int b0 = 2 * bp, c0 = 2 * cp;
        {
            float p = hee * invT, jo = mx[n][b0] * my[n][c0] * invT2;
            mi += p * (__logf(p + 1e-8f) - __logf(jo + 1e-8f));
        }
        {
            float p = heo * invT, jo = mx[n][b0] * my[n][c0 + 1] * invT2;
            mi += p * (__logf(p + 1e-8f) - __logf(jo + 1e-8f));
        }
        {
            float p = hoe * invT, jo = mx[n][b0 + 1] * my[n][c0] * invT2;
            mi += p * (__logf(p + 1e-8f) - __logf(jo + 1e-8f));
        }
        {
            float p = hoo * invT, jo = mx[n][b0 + 1] * my[n][c0 + 1] * invT2;
            mi += p * (__logf(p + 1e-8f) - __logf(jo + 1e-8f));
        }
    }
    #pragma unroll
    for (int o = 32; o > 0; o >>= 1) mi += __shfl_down(mi, o, 64);
    if ((tid & 63) == 0) red[tid >> 6] = mi;
    __syncthreads();
    if (tid == 0) {
        float t = 0.f;
        for (int i = 0; i < 16; ++i) t += red[i];
        out[0] = t;
    }
}

extern "C" void kernel_launch(void* const* d_in, const int* in_sizes, int n_in,
                              void* d_out, int out_size, void* d_ws, size_t ws_size,
                              hipStream_t stream) {
    const float* im1 = (const float*)d_in[0];
    const float* im2 = (const float*)d_in[1];
    float* out = (float*)d_out;
    float* hg  = (float*)d_ws;   // [8][32][32] f32 = 32 KB

    (void)hipMemsetAsync(d_ws, 0, NBATCH * 1024 * sizeof(float), stream);
    hgram_kernel<<<dim3(KSLICES, NBATCH), dim3(256), 0, stream>>>(im1, im2, hg);
    finalize_kernel<<<dim3(1), dim3(1024), 0, stream>>>(hg, out);
}